// Round 1
// baseline (11245.423 us; speedup 1.0000x reference)
//
#include <hip/hip_runtime.h>

// 2-layer LSTM (H=64, D=1), N=2048 samples, T=512 steps, fp32 throughout.
//
// Mapping: lane = hidden unit j (64 lanes), wave = 2 samples, block = 4 waves
// (8 samples), grid = 256 blocks (1 block/CU, forced by 128KB dynamic LDS).
// Weights per unit-lane = 768 floats: 384 register-resident across the whole
// T loop (W_hh1 full + W_ih2 k=0..31), 384 streamed per step from LDS
// (W_ih2 k=32..63 + W_hh2), [k][j] float4 layout -> conflict-free ds_read_b128.
// h broadcasts via v_readlane (VALU pipe), weights via LDS pipe.

#define TT 512
#define OUTT 511

__device__ __forceinline__ float rl(float v, int k) {
  return __int_as_float(__builtin_amdgcn_readlane(__float_as_int(v), k));
}
__device__ __forceinline__ float fast_rcp(float x) { return __builtin_amdgcn_rcpf(x); }
__device__ __forceinline__ float sigm(float x) { return fast_rcp(1.0f + __expf(-x)); }
__device__ __forceinline__ float tanh_f(float x) {
  x = fminf(15.0f, fmaxf(-15.0f, x));
  const float e = __expf(2.0f * x);
  return (e - 1.0f) * fast_rcp(e + 1.0f);
}

__global__ __launch_bounds__(256, 1) void lstm2_fused(
    const float* __restrict__ y, const float* __restrict__ Wih1,
    const float* __restrict__ Whh1, const float* __restrict__ bih1,
    const float* __restrict__ bhh1, const float* __restrict__ Wih2,
    const float* __restrict__ Whh2, const float* __restrict__ bih2,
    const float* __restrict__ bhh2, const float* __restrict__ Wlin,
    const float* __restrict__ blin, float* __restrict__ out) {
  extern __shared__ float4 smem[];
  float4* w2f = smem;        // [64][64] float4(gates) for W_ih2; rows 32..63 used in loop
  float4* w3f = smem + 4096; // phase A/B: W_hh1 temp; after phase C: W_hh2

  const int tid = threadIdx.x;
  const int wave = tid >> 6;
  const int lane = tid & 63;
  const int j = lane;

  // ---- Phase A: stage Whh1 (-> w3f temp) and Wih2 (-> w2f), transposed [k][j].g ----
  for (int p = wave; p < 256; p += 4) {   // p = g*64 + jj (row index)
    const int g = p >> 6, jj = p & 63;
    const float v1 = Whh1[p * 64 + lane]; // coalesced: k = lane
    const float v2 = Wih2[p * 64 + lane];
    ((float*)(w3f + lane * 64 + jj))[g] = v1;  // one-time conflicted transpose write
    ((float*)(w2f + lane * 64 + jj))[g] = v2;
  }
  __syncthreads();

  // ---- Phase B: pull register-resident weights (conflict-free b128 reads) ----
  float wm1[4][64];
#pragma unroll
  for (int k = 0; k < 64; ++k) {
    const float4 w = w3f[k * 64 + j];
    wm1[0][k] = w.x; wm1[1][k] = w.y; wm1[2][k] = w.z; wm1[3][k] = w.w;
  }
  float wm2[4][32];
#pragma unroll
  for (int k = 0; k < 32; ++k) {
    const float4 w = w2f[k * 64 + j];
    wm2[0][k] = w.x; wm2[1][k] = w.y; wm2[2][k] = w.z; wm2[3][k] = w.w;
  }
  __syncthreads();

  // ---- Phase C: stage Whh2 into w3f (overwrite Whh1 temp) ----
  for (int p = wave; p < 256; p += 4) {
    const int g = p >> 6, jj = p & 63;
    const float v3 = Whh2[p * 64 + lane];
    ((float*)(w3f + lane * 64 + jj))[g] = v3;
  }
  __syncthreads();

  // ---- per-lane constants ----
  float bc1[4], bc2[4], wx1[4];
#pragma unroll
  for (int g = 0; g < 4; ++g) {
    bc1[g] = bih1[g * 64 + j] + bhh1[g * 64 + j];
    bc2[g] = bih2[g * 64 + j] + bhh2[g * 64 + j];
    wx1[g] = Wih1[g * 64 + j];
  }
  const float wlj = Wlin[j];
  const float bl0 = blin[0];

  const int s0 = (blockIdx.x * 4 + wave) * 2;  // sample pair
  const float* ya = y + (size_t)s0 * TT;
  const float* yb = ya + TT;
  float* oa = out + (size_t)s0 * OUTT;
  float* ob = oa + OUTT;

  float h1a = 0.f, h1b = 0.f, c1a = 0.f, c1b = 0.f;
  float h2a = 0.f, h2b = 0.f, c2a = 0.f, c2b = 0.f;

#pragma unroll 1
  for (int tc = 0; tc < TT; tc += 64) {
    const float ycha = ya[tc + lane];  // 64 steps of input, coalesced
    const float ychb = yb[tc + lane];
#pragma unroll 1
    for (int tt = 0; tt < 64; ++tt) {
      const int t = tc + tt;
      const float xa = rl(ycha, tt);
      const float xb = rl(ychb, tt);

      // ---- Layer 1: gates = bc1 + x*wx1 + Whh1 @ h1 ----
      float Aa0 = bc1[0] + xa * wx1[0], Aa1 = bc1[1] + xa * wx1[1];
      float Aa2 = bc1[2] + xa * wx1[2], Aa3 = bc1[3] + xa * wx1[3];
      float Ab0 = bc1[0] + xb * wx1[0], Ab1 = bc1[1] + xb * wx1[1];
      float Ab2 = bc1[2] + xb * wx1[2], Ab3 = bc1[3] + xb * wx1[3];
#pragma unroll
      for (int k = 0; k < 64; ++k) {
        const float ha = rl(h1a, k), hb = rl(h1b, k);
        Aa0 += wm1[0][k] * ha; Aa1 += wm1[1][k] * ha;
        Aa2 += wm1[2][k] * ha; Aa3 += wm1[3][k] * ha;
        Ab0 += wm1[0][k] * hb; Ab1 += wm1[1][k] * hb;
        Ab2 += wm1[2][k] * hb; Ab3 += wm1[3][k] * hb;
      }
      {
        const float ia = sigm(Aa0), fa = sigm(Aa1), ga = tanh_f(Aa2), za = sigm(Aa3);
        c1a = fa * c1a + ia * ga;
        h1a = za * tanh_f(c1a);
        const float ib = sigm(Ab0), fb = sigm(Ab1), gb = tanh_f(Ab2), zb = sigm(Ab3);
        c1b = fb * c1b + ib * gb;
        h1b = zb * tanh_f(c1b);
      }

      // ---- Layer 2: gates = bc2 + Wih2 @ h1_new + Whh2 @ h2_old ----
      float Ba0 = bc2[0], Ba1 = bc2[1], Ba2 = bc2[2], Ba3 = bc2[3];
      float Bb0 = bc2[0], Bb1 = bc2[1], Bb2 = bc2[2], Bb3 = bc2[3];
#pragma unroll
      for (int k = 0; k < 32; ++k) {  // register half of Wih2
        const float ha = rl(h1a, k), hb = rl(h1b, k);
        Ba0 += wm2[0][k] * ha; Ba1 += wm2[1][k] * ha;
        Ba2 += wm2[2][k] * ha; Ba3 += wm2[3][k] * ha;
        Bb0 += wm2[0][k] * hb; Bb1 += wm2[1][k] * hb;
        Bb2 += wm2[2][k] * hb; Bb3 += wm2[3][k] * hb;
      }
#pragma unroll
      for (int k = 32; k < 64; ++k) {  // LDS half of Wih2
        const float4 w = w2f[k * 64 + j];
        const float ha = rl(h1a, k), hb = rl(h1b, k);
        Ba0 += w.x * ha; Ba1 += w.y * ha; Ba2 += w.z * ha; Ba3 += w.w * ha;
        Bb0 += w.x * hb; Bb1 += w.y * hb; Bb2 += w.z * hb; Bb3 += w.w * hb;
      }
#pragma unroll
      for (int k = 0; k < 64; ++k) {   // Whh2 from LDS, uses h2_old
        const float4 w = w3f[k * 64 + j];
        const float ha = rl(h2a, k), hb = rl(h2b, k);
        Ba0 += w.x * ha; Ba1 += w.y * ha; Ba2 += w.z * ha; Ba3 += w.w * ha;
        Bb0 += w.x * hb; Bb1 += w.y * hb; Bb2 += w.z * hb; Bb3 += w.w * hb;
      }
      {
        const float ia = sigm(Ba0), fa = sigm(Ba1), ga = tanh_f(Ba2), za = sigm(Ba3);
        c2a = fa * c2a + ia * ga;
        h2a = za * tanh_f(c2a);
        const float ib = sigm(Bb0), fb = sigm(Bb1), gb = tanh_f(Bb2), zb = sigm(Bb3);
        c2b = fb * c2b + ib * gb;
        h2b = zb * tanh_f(c2b);
      }

      // ---- output: out[s][t-1] = Wlin . h2 + blin (skip t=0) ----
      float pa = wlj * h2a, pb = wlj * h2b;
#pragma unroll
      for (int m = 32; m >= 1; m >>= 1) {
        pa += __shfl_xor(pa, m, 64);
        pb += __shfl_xor(pb, m, 64);
      }
      if (t >= 1 && lane == 0) {
        oa[t - 1] = pa + bl0;
        ob[t - 1] = pb + bl0;
      }
    }
  }
}

extern "C" void kernel_launch(void* const* d_in, const int* in_sizes, int n_in,
                              void* d_out, int out_size, void* d_ws, size_t ws_size,
                              hipStream_t stream) {
  const float* y    = (const float*)d_in[0];
  const float* Wih1 = (const float*)d_in[1];
  const float* Whh1 = (const float*)d_in[2];
  const float* bih1 = (const float*)d_in[3];
  const float* bhh1 = (const float*)d_in[4];
  const float* Wih2 = (const float*)d_in[5];
  const float* Whh2 = (const float*)d_in[6];
  const float* bih2 = (const float*)d_in[7];
  const float* bhh2 = (const float*)d_in[8];
  const float* Wlin = (const float*)d_in[9];
  const float* blin = (const float*)d_in[10];
  // d_in[11] = pre_output_len (fixed at 1 per the reference; hardcoded)
  float* out = (float*)d_out;

  hipFuncSetAttribute((const void*)lstm2_fused,
                      hipFuncAttributeMaxDynamicSharedMemorySize, 131072);
  lstm2_fused<<<dim3(256), dim3(256), 131072, stream>>>(
      y, Wih1, Whh1, bih1, bhh1, Wih2, Whh2, bih2, bhh2, Wlin, blin, out);
}

// Round 2
// 3400.216 us; speedup vs baseline: 3.3073x; 3.3073x over previous
//
#include <hip/hip_runtime.h>

// 2-layer LSTM (H=64, D=1), N=2048 samples, T=512 steps, fp32 throughout.
//
// Mapping: lane = hidden unit j (64 lanes), wave = 2 samples, block = 4 waves
// (8 samples), grid = 256 blocks (1 block/CU; 152KB dynamic LDS).
//
// Weight split (fits the 256-addressable-VGPR file; R1 spilled at 384):
//   registers: Whh1 k=0..39            -> 160 floats/lane
//   LDS:       Whh1 k=40..63 (w1f), Wih2 (w2f), Whh2 (w3f)
//              = 152 float4/lane/step, [k][j] float4 layout, conflict-free
//              ds_read_b128. h broadcasts via v_readlane (VALU/SALU operand).

#define TT 512
#define OUTT 511
#define RK 40  // Whh1 rows kept in registers

__device__ __forceinline__ float rl(float v, int k) {
  return __int_as_float(__builtin_amdgcn_readlane(__float_as_int(v), k));
}
__device__ __forceinline__ float fast_rcp(float x) { return __builtin_amdgcn_rcpf(x); }
__device__ __forceinline__ float sigm(float x) { return fast_rcp(1.0f + __expf(-x)); }
__device__ __forceinline__ float tanh_f(float x) {
  x = fminf(15.0f, fmaxf(-15.0f, x));
  const float e = __expf(2.0f * x);
  return (e - 1.0f) * fast_rcp(e + 1.0f);
}

__global__ __launch_bounds__(256, 1) void lstm2_fused(
    const float* __restrict__ y, const float* __restrict__ Wih1,
    const float* __restrict__ Whh1, const float* __restrict__ bih1,
    const float* __restrict__ bhh1, const float* __restrict__ Wih2,
    const float* __restrict__ Whh2, const float* __restrict__ bih2,
    const float* __restrict__ bhh2, const float* __restrict__ Wlin,
    const float* __restrict__ blin, float* __restrict__ out) {
  extern __shared__ float4 smem[];
  float4* w1f = smem;                        // [24][64] Whh1 rows k=40..63
  float4* w2f = smem + 24 * 64;              // [64][64] Wih2 (phase A: Whh1 temp)
  float4* w3f = smem + 24 * 64 + 64 * 64;    // [64][64] Whh2

  const int tid = threadIdx.x;
  const int wave = tid >> 6;
  const int lane = tid & 63;
  const int j = lane;

  // ---- Phase A: stage Whh1 transposed [k][j].g into w2f (temp) ----
  for (int p = wave; p < 256; p += 4) {       // p = g*64 + jj (row index)
    const int g = p >> 6, jj = p & 63;
    ((float*)(w2f + lane * 64 + jj))[g] = Whh1[p * 64 + lane];  // one-time conflicted write
  }
  __syncthreads();

  // ---- Phase B: pull register Whh1 (k<RK), copy k>=RK rows to w1f ----
  float wm1[4][RK];
#pragma unroll
  for (int k = 0; k < RK; ++k) {
    const float4 w = w2f[k * 64 + j];
    wm1[0][k] = w.x; wm1[1][k] = w.y; wm1[2][k] = w.z; wm1[3][k] = w.w;
  }
  for (int k = RK + wave; k < 64; k += 4)     // conflict-free b128 copy
    w1f[(k - RK) * 64 + lane] = w2f[k * 64 + lane];
  __syncthreads();

  // ---- Phase C: stage Wih2 -> w2f (overwrite), Whh2 -> w3f ----
  for (int p = wave; p < 256; p += 4) {
    const int g = p >> 6, jj = p & 63;
    ((float*)(w2f + lane * 64 + jj))[g] = Wih2[p * 64 + lane];
    ((float*)(w3f + lane * 64 + jj))[g] = Whh2[p * 64 + lane];
  }
  __syncthreads();

  // ---- per-lane constants ----
  float bc1[4], bc2[4], wx1[4];
#pragma unroll
  for (int g = 0; g < 4; ++g) {
    bc1[g] = bih1[g * 64 + j] + bhh1[g * 64 + j];
    bc2[g] = bih2[g * 64 + j] + bhh2[g * 64 + j];
    wx1[g] = Wih1[g * 64 + j];
  }
  const float wlj = Wlin[j];
  const float bl0 = blin[0];

  const int s0 = (blockIdx.x * 4 + wave) * 2;  // sample pair
  const float* ya = y + (size_t)s0 * TT;
  const float* yb = ya + TT;
  float* oa = out + (size_t)s0 * OUTT;
  float* ob = oa + OUTT;

  float h1a = 0.f, h1b = 0.f, c1a = 0.f, c1b = 0.f;
  float h2a = 0.f, h2b = 0.f, c2a = 0.f, c2b = 0.f;

#pragma unroll 1
  for (int tc = 0; tc < TT; tc += 64) {
    const float ycha = ya[tc + lane];  // 64 steps of input, coalesced
    const float ychb = yb[tc + lane];
#pragma unroll 1
    for (int tt = 0; tt < 64; ++tt) {
      const int t = tc + tt;
      const float xa = rl(ycha, tt);
      const float xb = rl(ychb, tt);

      // ---- Layer 1: gates = bc1 + x*wx1 + Whh1 @ h1 ----
      float Aa0 = bc1[0] + xa * wx1[0], Aa1 = bc1[1] + xa * wx1[1];
      float Aa2 = bc1[2] + xa * wx1[2], Aa3 = bc1[3] + xa * wx1[3];
      float Ab0 = bc1[0] + xb * wx1[0], Ab1 = bc1[1] + xb * wx1[1];
      float Ab2 = bc1[2] + xb * wx1[2], Ab3 = bc1[3] + xb * wx1[3];
#pragma unroll
      for (int k = 0; k < RK; ++k) {           // register half of Whh1
        const float ha = rl(h1a, k), hb = rl(h1b, k);
        Aa0 += wm1[0][k] * ha; Aa1 += wm1[1][k] * ha;
        Aa2 += wm1[2][k] * ha; Aa3 += wm1[3][k] * ha;
        Ab0 += wm1[0][k] * hb; Ab1 += wm1[1][k] * hb;
        Ab2 += wm1[2][k] * hb; Ab3 += wm1[3][k] * hb;
      }
#pragma unroll
      for (int k = RK; k < 64; ++k) {          // LDS tail of Whh1
        const float4 w = w1f[(k - RK) * 64 + j];
        const float ha = rl(h1a, k), hb = rl(h1b, k);
        Aa0 += w.x * ha; Aa1 += w.y * ha; Aa2 += w.z * ha; Aa3 += w.w * ha;
        Ab0 += w.x * hb; Ab1 += w.y * hb; Ab2 += w.z * hb; Ab3 += w.w * hb;
      }
      {
        const float ia = sigm(Aa0), fa = sigm(Aa1), ga = tanh_f(Aa2), za = sigm(Aa3);
        c1a = fa * c1a + ia * ga;
        h1a = za * tanh_f(c1a);
        const float ib = sigm(Ab0), fb = sigm(Ab1), gb = tanh_f(Ab2), zb = sigm(Ab3);
        c1b = fb * c1b + ib * gb;
        h1b = zb * tanh_f(c1b);
      }

      // ---- Layer 2: gates = bc2 + Wih2 @ h1_new + Whh2 @ h2_old ----
      float Ba0 = bc2[0], Ba1 = bc2[1], Ba2 = bc2[2], Ba3 = bc2[3];
      float Bb0 = bc2[0], Bb1 = bc2[1], Bb2 = bc2[2], Bb3 = bc2[3];
#pragma unroll
      for (int k = 0; k < 64; ++k) {           // Wih2 from LDS, uses h1_new
        const float4 w = w2f[k * 64 + j];
        const float ha = rl(h1a, k), hb = rl(h1b, k);
        Ba0 += w.x * ha; Ba1 += w.y * ha; Ba2 += w.z * ha; Ba3 += w.w * ha;
        Bb0 += w.x * hb; Bb1 += w.y * hb; Bb2 += w.z * hb; Bb3 += w.w * hb;
      }
#pragma unroll
      for (int k = 0; k < 64; ++k) {           // Whh2 from LDS, uses h2_old
        const float4 w = w3f[k * 64 + j];
        const float ha = rl(h2a, k), hb = rl(h2b, k);
        Ba0 += w.x * ha; Ba1 += w.y * ha; Ba2 += w.z * ha; Ba3 += w.w * ha;
        Bb0 += w.x * hb; Bb1 += w.y * hb; Bb2 += w.z * hb; Bb3 += w.w * hb;
      }
      {
        const float ia = sigm(Ba0), fa = sigm(Ba1), ga = tanh_f(Ba2), za = sigm(Ba3);
        c2a = fa * c2a + ia * ga;
        h2a = za * tanh_f(c2a);
        const float ib = sigm(Bb0), fb = sigm(Bb1), gb = tanh_f(Bb2), zb = sigm(Bb3);
        c2b = fb * c2b + ib * gb;
        h2b = zb * tanh_f(c2b);
      }

      // ---- output: out[s][t-1] = Wlin . h2 + blin (skip t=0) ----
      float pa = wlj * h2a, pb = wlj * h2b;
#pragma unroll
      for (int m = 32; m >= 1; m >>= 1) {
        pa += __shfl_xor(pa, m, 64);
        pb += __shfl_xor(pb, m, 64);
      }
      if (t >= 1 && lane == 0) {
        oa[t - 1] = pa + bl0;
        ob[t - 1] = pb + bl0;
      }
    }
  }
}

extern "C" void kernel_launch(void* const* d_in, const int* in_sizes, int n_in,
                              void* d_out, int out_size, void* d_ws, size_t ws_size,
                              hipStream_t stream) {
  const float* y    = (const float*)d_in[0];
  const float* Wih1 = (const float*)d_in[1];
  const float* Whh1 = (const float*)d_in[2];
  const float* bih1 = (const float*)d_in[3];
  const float* bhh1 = (const float*)d_in[4];
  const float* Wih2 = (const float*)d_in[5];
  const float* Whh2 = (const float*)d_in[6];
  const float* bih2 = (const float*)d_in[7];
  const float* bhh2 = (const float*)d_in[8];
  const float* Wlin = (const float*)d_in[9];
  const float* blin = (const float*)d_in[10];
  float* out = (float*)d_out;

  const int lds_bytes = (24 * 64 + 64 * 64 + 64 * 64) * 16;  // 155648 B
  hipFuncSetAttribute((const void*)lstm2_fused,
                      hipFuncAttributeMaxDynamicSharedMemorySize, lds_bytes);
  lstm2_fused<<<dim3(256), dim3(256), lds_bytes, stream>>>(
      y, Wih1, Whh1, bih1, bhh1, Wih2, Whh2, bih2, bhh2, Wlin, blin, out);
}

// Round 3
// 906.725 us; speedup vs baseline: 12.4022x; 3.7500x over previous
//
#include <hip/hip_runtime.h>

// 2-layer LSTM (H=64, D=1), N=2048, T=512 — MFMA bf16 3-term split precision.
//
// Block = 16 samples = 4 waves (gate-split), grid = 128 blocks (1/CU).
// Wave w owns cell rows [16w,16w+16) = gate row-tiles {w,w+4,w+8,w+12} (i,f,g,o).
// Per matvec: G = Whi*hhi + Whi*hlo + Wlo*hhi  (all residual terms <= 2^-17 rel).
// Whi A-fragments VGPR-resident (96 VGPR); Wlo streamed from LDS (96KB);
// h exchanged via double-buffered bf16 hi/lo LDS planes [16 s][pitch 144B].
// A and B packed with identical (g,e)->k map => layout-permutation-proof.

typedef __attribute__((ext_vector_type(8))) short short8;
typedef __attribute__((ext_vector_type(4))) float f32x4;

#define WLO 0        // 96KB: 24 frags/wave * 4 waves * 1024B
#define XP  98304    // 32KB: x[t][s] f32
#define HP  131072   // 18432B: [buf2][plane4][16 s][144B]  planes: h1hi,h1lo,h2hi,h2lo
#define OP  149504   // 256B: outp[w][s]
#define LDS_BYTES 149760

__device__ __forceinline__ float fast_rcp(float x) { return __builtin_amdgcn_rcpf(x); }
__device__ __forceinline__ float sigm(float x) { return fast_rcp(1.0f + __expf(-x)); }
__device__ __forceinline__ float tanh_f(float x) {
  x = fminf(15.0f, fmaxf(-15.0f, x));
  const float e = __expf(2.0f * x);
  return (e - 1.0f) * fast_rcp(e + 1.0f);
}
__device__ __forceinline__ unsigned short bf_rne(float f) {
  unsigned u = __float_as_uint(f);
  return (unsigned short)((u + 0x7FFFu + ((u >> 16) & 1u)) >> 16);
}
__device__ __forceinline__ void split8(const float* p, short8& hi, short8& lo) {
#pragma unroll
  for (int e = 0; e < 8; ++e) {
    float v = p[e];
    unsigned short h = bf_rne(v);
    float hf = __uint_as_float(((unsigned)h) << 16);
    hi[e] = (short)h;
    lo[e] = (short)bf_rne(v - hf);
  }
}
__device__ __forceinline__ unsigned cvt_pk(float a, float b) {  // low16=bf16(a), high16=bf16(b)
  unsigned r;
  asm("v_cvt_pk_bf16_f32 %0, %1, %2" : "=v"(r) : "v"(a), "v"(b));
  return r;
}
__device__ __forceinline__ f32x4 mfma16(short8 a, short8 b, f32x4 c) {
  return __builtin_amdgcn_mfma_f32_16x16x32_bf16(a, b, c, 0, 0, 0);
}

__global__ __launch_bounds__(256, 1) void lstm2_mfma(
    const float* __restrict__ y, const float* __restrict__ Wih1,
    const float* __restrict__ Whh1, const float* __restrict__ bih1,
    const float* __restrict__ bhh1, const float* __restrict__ Wih2,
    const float* __restrict__ Whh2, const float* __restrict__ bih2,
    const float* __restrict__ bhh2, const float* __restrict__ Wlin,
    const float* __restrict__ blin, float* __restrict__ out) {
  extern __shared__ char smem[];
  const int tid = threadIdx.x;
  const int w = tid >> 6;          // wave 0..3
  const int lane = tid & 63;
  const int g = lane >> 4;         // k-group 0..3
  const int s = lane & 15;         // sample (B/D col) AND A row-within-tile
  const int s0 = blockIdx.x * 16;

  // ---- stage x[t][s] (coalesced over t) ----
  for (int i = tid; i < 16 * 512; i += 256) {
    const int ss = i >> 9, t = i & 511;
    *(float*)(smem + XP + t * 64 + ss * 4) = y[(size_t)(s0 + ss) * 512 + t];
  }
  // ---- zero h planes (both buffers) ----
  for (int i = tid; i < 18432 / 4; i += 256) *(float*)(smem + HP + i * 4) = 0.f;

  // ---- weight fragments: hi -> VGPR, lo -> LDS (pre-swizzled frag layout) ----
  short8 a1[4][2], a2[4][4];
  {
    const int row = 16 * w + s;  // within-gate row; gate p adds p*64
    short8 hi, lo;
#pragma unroll
    for (int p = 0; p < 4; ++p) {
#pragma unroll
      for (int c = 0; c < 2; ++c) {
        split8(Whh1 + (size_t)(p * 64 + row) * 64 + 32 * c + 8 * g, hi, lo);
        a1[p][c] = hi;
        *(short8*)(smem + WLO + w * 24576 + (p * 2 + c) * 1024 + lane * 16) = lo;
      }
#pragma unroll
      for (int c = 0; c < 4; ++c) {
        const float* src = (c < 2) ? (Wih2 + (size_t)(p * 64 + row) * 64 + 32 * c + 8 * g)
                                   : (Whh2 + (size_t)(p * 64 + row) * 64 + 32 * (c - 2) + 8 * g);
        split8(src, hi, lo);
        a2[p][c] = hi;
        *(short8*)(smem + WLO + w * 24576 + (8 + p * 4 + c) * 1024 + lane * 16) = lo;
      }
    }
  }

  // ---- per-lane constants (indexed by D layout: row = 4g + r within tile) ----
  float bias1c[4][4], wih1c[4][4], bias2c[4][4], wlinc[4];
#pragma unroll
  for (int p = 0; p < 4; ++p)
#pragma unroll
    for (int r = 0; r < 4; ++r) {
      const int row = p * 64 + 16 * w + 4 * g + r;
      bias1c[p][r] = bih1[row] + bhh1[row];
      wih1c[p][r] = Wih1[row];
      bias2c[p][r] = bih2[row] + bhh2[row];
    }
#pragma unroll
  for (int r = 0; r < 4; ++r) wlinc[r] = Wlin[16 * w + 4 * g + r];
  const float bl0 = blin[0];

  float c1[4] = {0.f, 0.f, 0.f, 0.f}, c2[4] = {0.f, 0.f, 0.f, 0.f};
  __syncthreads();

#pragma unroll 1
  for (int t = 0; t < 512; ++t) {
    const int rb = HP + (t & 1) * 9216;        // read buffer (h old)
    const int wb = HP + ((t + 1) & 1) * 9216;  // write buffer (h new)
    const float x = *(const float*)(smem + XP + t * 64 + s * 4);

    // ================= layer 1 =================
    f32x4 acc[4];
#pragma unroll
    for (int p = 0; p < 4; ++p)
#pragma unroll
      for (int r = 0; r < 4; ++r) acc[p][r] = bias1c[p][r] + wih1c[p][r] * x;

#pragma unroll
    for (int c = 0; c < 2; ++c) {
      const int boff = s * 144 + 64 * c + 16 * g;
      const short8 Bh = *(const short8*)(smem + rb + 0 * 2304 + boff);
      const short8 Bl = *(const short8*)(smem + rb + 1 * 2304 + boff);
      short8 L[4];
#pragma unroll
      for (int p = 0; p < 4; ++p)
        L[p] = *(const short8*)(smem + WLO + w * 24576 + (p * 2 + c) * 1024 + lane * 16);
#pragma unroll
      for (int p = 0; p < 4; ++p) acc[p] = mfma16(a1[p][c], Bh, acc[p]);
#pragma unroll
      for (int p = 0; p < 4; ++p) acc[p] = mfma16(a1[p][c], Bl, acc[p]);
#pragma unroll
      for (int p = 0; p < 4; ++p) acc[p] = mfma16(L[p], Bh, acc[p]);
    }

    float h1n[4];
#pragma unroll
    for (int r = 0; r < 4; ++r) {
      const float ig = sigm(acc[0][r]), fg = sigm(acc[1][r]);
      const float gg = tanh_f(acc[2][r]), og = sigm(acc[3][r]);
      c1[r] = fg * c1[r] + ig * gg;
      h1n[r] = og * tanh_f(c1[r]);
    }
    {  // pack h1 -> bf16 hi/lo, write planes 0,1 of write-buffer
      const unsigned hA = cvt_pk(h1n[0], h1n[1]), hB = cvt_pk(h1n[2], h1n[3]);
      const float l0 = h1n[0] - __uint_as_float(hA << 16);
      const float l1 = h1n[1] - __uint_as_float(hA & 0xFFFF0000u);
      const float l2 = h1n[2] - __uint_as_float(hB << 16);
      const float l3 = h1n[3] - __uint_as_float(hB & 0xFFFF0000u);
      const unsigned lA = cvt_pk(l0, l1), lB = cvt_pk(l2, l3);
      const int hoff = s * 144 + 32 * w + 8 * g;
      *(unsigned*)(smem + wb + 0 * 2304 + hoff) = hA;
      *(unsigned*)(smem + wb + 0 * 2304 + hoff + 4) = hB;
      *(unsigned*)(smem + wb + 1 * 2304 + hoff) = lA;
      *(unsigned*)(smem + wb + 1 * 2304 + hoff + 4) = lB;
    }
    __syncthreads();  // h1new visible; outp(t-1) reads done

    // ================= layer 2 =================
    f32x4 acc2[4];
#pragma unroll
    for (int p = 0; p < 4; ++p)
#pragma unroll
      for (int r = 0; r < 4; ++r) acc2[p][r] = bias2c[p][r];

#pragma unroll
    for (int c = 0; c < 4; ++c) {
      const int pl = (c < 2) ? 0 : 2;     // h1 planes vs h2 planes
      const int bb = (c < 2) ? wb : rb;   // h1 NEW, h2 OLD
      const int boff = s * 144 + 64 * (c & 1) + 16 * g;
      const short8 Bh = *(const short8*)(smem + bb + (pl + 0) * 2304 + boff);
      const short8 Bl = *(const short8*)(smem + bb + (pl + 1) * 2304 + boff);
      short8 L[4];
#pragma unroll
      for (int p = 0; p < 4; ++p)
        L[p] = *(const short8*)(smem + WLO + w * 24576 + (8 + p * 4 + c) * 1024 + lane * 16);
#pragma unroll
      for (int p = 0; p < 4; ++p) acc2[p] = mfma16(a2[p][c], Bh, acc2[p]);
#pragma unroll
      for (int p = 0; p < 4; ++p) acc2[p] = mfma16(a2[p][c], Bl, acc2[p]);
#pragma unroll
      for (int p = 0; p < 4; ++p) acc2[p] = mfma16(L[p], Bh, acc2[p]);
    }

    float h2n[4];
#pragma unroll
    for (int r = 0; r < 4; ++r) {
      const float ig = sigm(acc2[0][r]), fg = sigm(acc2[1][r]);
      const float gg = tanh_f(acc2[2][r]), og = sigm(acc2[3][r]);
      c2[r] = fg * c2[r] + ig * gg;
      h2n[r] = og * tanh_f(c2[r]);
    }
    {  // pack h2 -> planes 2,3 of write-buffer
      const unsigned hA = cvt_pk(h2n[0], h2n[1]), hB = cvt_pk(h2n[2], h2n[3]);
      const float l0 = h2n[0] - __uint_as_float(hA << 16);
      const float l1 = h2n[1] - __uint_as_float(hA & 0xFFFF0000u);
      const float l2 = h2n[2] - __uint_as_float(hB << 16);
      const float l3 = h2n[3] - __uint_as_float(hB & 0xFFFF0000u);
      const unsigned lA = cvt_pk(l0, l1), lB = cvt_pk(l2, l3);
      const int hoff = s * 144 + 32 * w + 8 * g;
      *(unsigned*)(smem + wb + 2 * 2304 + hoff) = hA;
      *(unsigned*)(smem + wb + 2 * 2304 + hoff + 4) = hB;
      *(unsigned*)(smem + wb + 3 * 2304 + hoff) = lA;
      *(unsigned*)(smem + wb + 3 * 2304 + hoff + 4) = lB;
    }

    // ---- output partial: out[s] = sum_j Wlin[j] h2[j][s] + b ----
    float pw = wlinc[0] * h2n[0];
    pw = fmaf(wlinc[1], h2n[1], pw);
    pw = fmaf(wlinc[2], h2n[2], pw);
    pw = fmaf(wlinc[3], h2n[3], pw);
    pw += __shfl_xor(pw, 16, 64);
    pw += __shfl_xor(pw, 32, 64);
    if (g == 0) *(float*)(smem + OP + w * 64 + s * 4) = pw;
    __syncthreads();  // h2new + outp visible

    const float oo = *(const float*)(smem + OP + s * 4) +
                     *(const float*)(smem + OP + 64 + s * 4) +
                     *(const float*)(smem + OP + 128 + s * 4) +
                     *(const float*)(smem + OP + 192 + s * 4) + bl0;
    if (w == 0 && g == 0 && t >= 1) out[(size_t)(s0 + s) * 511 + t - 1] = oo;
  }
}

extern "C" void kernel_launch(void* const* d_in, const int* in_sizes, int n_in,
                              void* d_out, int out_size, void* d_ws, size_t ws_size,
                              hipStream_t stream) {
  const float* y    = (const float*)d_in[0];
  const float* Wih1 = (const float*)d_in[1];
  const float* Whh1 = (const float*)d_in[2];
  const float* bih1 = (const float*)d_in[3];
  const float* bhh1 = (const float*)d_in[4];
  const float* Wih2 = (const float*)d_in[5];
  const float* Whh2 = (const float*)d_in[6];
  const float* bih2 = (const float*)d_in[7];
  const float* bhh2 = (const float*)d_in[8];
  const float* Wlin = (const float*)d_in[9];
  const float* blin = (const float*)d_in[10];
  float* out = (float*)d_out;

  hipFuncSetAttribute((const void*)lstm2_mfma,
                      hipFuncAttributeMaxDynamicSharedMemorySize, LDS_BYTES);
  lstm2_mfma<<<dim3(128), dim3(256), LDS_BYTES, stream>>>(
      y, Wih1, Whh1, bih1, bhh1, Wih2, Whh2, bih2, bhh2, Wlin, blin, out);
}

// Round 4
// 848.049 us; speedup vs baseline: 13.2603x; 1.0692x over previous
//
#include <hip/hip_runtime.h>

// 2-layer LSTM (H=64, D=1), N=2048, T=512 — MFMA bf16 3-term split precision.
//
// Block = 16 samples = 4 waves (gate-split), grid = 128 blocks (1/CU).
// Wave w owns cell rows [16w,16w+16) = gate row-tiles {w,w+4,w+8,w+12}.
// Per matvec: G = Whi*hhi + Whi*hlo + Wlo*hhi  (residual terms <= 2^-17 rel).
// R4: ALL weight fragments (hi+lo = 192 regs/lane) live in the unified
// VGPR+AGPR file (512 regs/lane, MFMA reads A from AGPR). Per-step LDS is
// only the 12 B-fragment ds_read_b128 + h-plane writes. XP re-laid out to
// [s][pitch 2064] (conflict-free). h2-old B-frags hoisted above barrier 1.

typedef __attribute__((ext_vector_type(8))) short short8;
typedef __attribute__((ext_vector_type(4))) float f32x4;

#define XPITCH 2064
#define XP  0                       // 16 * 2064 = 33024 B: x[s][t] f32, padded pitch
#define HP  33024                   // 18432 B: [buf2][plane4][16 s][144 B]
#define OP  51456                   // 256 B: outp[w][s]
#define LDS_BYTES 51712

__device__ __forceinline__ float fast_rcp(float x) { return __builtin_amdgcn_rcpf(x); }
__device__ __forceinline__ float sigm(float x) { return fast_rcp(1.0f + __expf(-x)); }
__device__ __forceinline__ float tanh_f(float x) {
  x = fminf(15.0f, fmaxf(-15.0f, x));
  const float e = __expf(2.0f * x);
  return (e - 1.0f) * fast_rcp(e + 1.0f);
}
__device__ __forceinline__ unsigned short bf_rne(float f) {
  unsigned u = __float_as_uint(f);
  return (unsigned short)((u + 0x7FFFu + ((u >> 16) & 1u)) >> 16);
}
__device__ __forceinline__ void split8(const float* p, short8& hi, short8& lo) {
#pragma unroll
  for (int e = 0; e < 8; ++e) {
    float v = p[e];
    unsigned short h = bf_rne(v);
    float hf = __uint_as_float(((unsigned)h) << 16);
    hi[e] = (short)h;
    lo[e] = (short)bf_rne(v - hf);
  }
}
__device__ __forceinline__ unsigned cvt_pk(float a, float b) {  // lo16=bf16(a), hi16=bf16(b)
  unsigned r;
  asm("v_cvt_pk_bf16_f32 %0, %1, %2" : "=v"(r) : "v"(a), "v"(b));
  return r;
}
__device__ __forceinline__ f32x4 mfma16(short8 a, short8 b, f32x4 c) {
  return __builtin_amdgcn_mfma_f32_16x16x32_bf16(a, b, c, 0, 0, 0);
}

__global__ __launch_bounds__(256, 1) void lstm2_mfma(
    const float* __restrict__ y, const float* __restrict__ Wih1,
    const float* __restrict__ Whh1, const float* __restrict__ bih1,
    const float* __restrict__ bhh1, const float* __restrict__ Wih2,
    const float* __restrict__ Whh2, const float* __restrict__ bih2,
    const float* __restrict__ bhh2, const float* __restrict__ Wlin,
    const float* __restrict__ blin, float* __restrict__ out) {
  extern __shared__ char smem[];
  const int tid = threadIdx.x;
  const int w = tid >> 6;          // wave 0..3
  const int lane = tid & 63;
  const int g = lane >> 4;         // k-group 0..3
  const int s = lane & 15;         // sample col AND A row-within-tile
  const int s0 = blockIdx.x * 16;

  // ---- stage x: XP[s][t], consecutive tid -> consecutive t (conflict-free) ----
  for (int i = tid; i < 16 * 512; i += 256) {
    const int ss = i >> 9, t = i & 511;
    *(float*)(smem + XP + ss * XPITCH + t * 4) = y[(size_t)(s0 + ss) * 512 + t];
  }
  // ---- zero h planes (both buffers), consecutive writes ----
  for (int i = tid; i < 18432 / 4; i += 256) *(float*)(smem + HP + i * 4) = 0.f;

  // ---- weight fragments: hi AND lo register-resident (unified VGPR/AGPR file) ----
  short8 a1h[4][2], a1l[4][2], a2h[4][4], a2l[4][4];
  {
    const int row = 16 * w + s;  // within-gate row; gate p adds p*64
#pragma unroll
    for (int p = 0; p < 4; ++p) {
#pragma unroll
      for (int c = 0; c < 2; ++c)
        split8(Whh1 + (size_t)(p * 64 + row) * 64 + 32 * c + 8 * g, a1h[p][c], a1l[p][c]);
#pragma unroll
      for (int c = 0; c < 4; ++c) {
        const float* src = (c < 2) ? (Wih2 + (size_t)(p * 64 + row) * 64 + 32 * c + 8 * g)
                                   : (Whh2 + (size_t)(p * 64 + row) * 64 + 32 * (c - 2) + 8 * g);
        split8(src, a2h[p][c], a2l[p][c]);
      }
    }
  }

  // ---- per-lane constants (D layout: row = 4g + r within tile) ----
  float bias1c[4][4], wih1c[4][4], bias2c[4][4], wlinc[4];
#pragma unroll
  for (int p = 0; p < 4; ++p)
#pragma unroll
    for (int r = 0; r < 4; ++r) {
      const int row = p * 64 + 16 * w + 4 * g + r;
      bias1c[p][r] = bih1[row] + bhh1[row];
      wih1c[p][r] = Wih1[row];
      bias2c[p][r] = bih2[row] + bhh2[row];
    }
#pragma unroll
  for (int r = 0; r < 4; ++r) wlinc[r] = Wlin[16 * w + 4 * g + r];
  const float bl0 = blin[0];

  float c1[4] = {0.f, 0.f, 0.f, 0.f}, c2[4] = {0.f, 0.f, 0.f, 0.f};
  __syncthreads();

#pragma unroll 1
  for (int t = 0; t < 512; ++t) {
    const int rb = HP + (t & 1) * 9216;        // read buffer (h old)
    const int wb = HP + ((t + 1) & 1) * 9216;  // write buffer (h new)
    const float x = *(const float*)(smem + XP + s * XPITCH + t * 4);

    // ---- hoist: h2-old B-fragments (written last step, safe to read now) ----
    short8 B2h[2], B2l[2];
#pragma unroll
    for (int c = 0; c < 2; ++c) {
      const int boff = s * 144 + 64 * c + 16 * g;
      B2h[c] = *(const short8*)(smem + rb + 2 * 2304 + boff);
      B2l[c] = *(const short8*)(smem + rb + 3 * 2304 + boff);
    }

    // ================= layer 1 =================
    f32x4 acc[4];
#pragma unroll
    for (int p = 0; p < 4; ++p)
#pragma unroll
      for (int r = 0; r < 4; ++r) acc[p][r] = bias1c[p][r] + wih1c[p][r] * x;

#pragma unroll
    for (int c = 0; c < 2; ++c) {
      const int boff = s * 144 + 64 * c + 16 * g;
      const short8 Bh = *(const short8*)(smem + rb + 0 * 2304 + boff);
      const short8 Bl = *(const short8*)(smem + rb + 1 * 2304 + boff);
#pragma unroll
      for (int p = 0; p < 4; ++p) acc[p] = mfma16(a1h[p][c], Bh, acc[p]);
#pragma unroll
      for (int p = 0; p < 4; ++p) acc[p] = mfma16(a1h[p][c], Bl, acc[p]);
#pragma unroll
      for (int p = 0; p < 4; ++p) acc[p] = mfma16(a1l[p][c], Bh, acc[p]);
    }

    float h1n[4];
#pragma unroll
    for (int r = 0; r < 4; ++r) {
      const float ig = sigm(acc[0][r]), fg = sigm(acc[1][r]);
      const float gg = tanh_f(acc[2][r]), og = sigm(acc[3][r]);
      c1[r] = fg * c1[r] + ig * gg;
      h1n[r] = og * tanh_f(c1[r]);
    }
    {  // pack h1 -> planes 0,1 of write-buffer (8B stores)
      const unsigned hA = cvt_pk(h1n[0], h1n[1]), hB = cvt_pk(h1n[2], h1n[3]);
      const float l0 = h1n[0] - __uint_as_float(hA << 16);
      const float l1 = h1n[1] - __uint_as_float(hA & 0xFFFF0000u);
      const float l2 = h1n[2] - __uint_as_float(hB << 16);
      const float l3 = h1n[3] - __uint_as_float(hB & 0xFFFF0000u);
      const unsigned lA = cvt_pk(l0, l1), lB = cvt_pk(l2, l3);
      const int hoff = s * 144 + 32 * w + 8 * g;
      *(uint2*)(smem + wb + 0 * 2304 + hoff) = make_uint2(hA, hB);
      *(uint2*)(smem + wb + 1 * 2304 + hoff) = make_uint2(lA, lB);
    }
    __syncthreads();  // h1new visible

    // ================= layer 2 =================
    f32x4 acc2[4];
#pragma unroll
    for (int p = 0; p < 4; ++p)
#pragma unroll
      for (int r = 0; r < 4; ++r) acc2[p][r] = bias2c[p][r];

#pragma unroll
    for (int c = 0; c < 2; ++c) {  // h1 NEW from wb planes 0,1
      const int boff = s * 144 + 64 * c + 16 * g;
      const short8 Bh = *(const short8*)(smem + wb + 0 * 2304 + boff);
      const short8 Bl = *(const short8*)(smem + wb + 1 * 2304 + boff);
#pragma unroll
      for (int p = 0; p < 4; ++p) acc2[p] = mfma16(a2h[p][c], Bh, acc2[p]);
#pragma unroll
      for (int p = 0; p < 4; ++p) acc2[p] = mfma16(a2h[p][c], Bl, acc2[p]);
#pragma unroll
      for (int p = 0; p < 4; ++p) acc2[p] = mfma16(a2l[p][c], Bh, acc2[p]);
    }
#pragma unroll
    for (int c = 0; c < 2; ++c) {  // h2 OLD (hoisted loads)
#pragma unroll
      for (int p = 0; p < 4; ++p) acc2[p] = mfma16(a2h[p][c + 2], B2h[c], acc2[p]);
#pragma unroll
      for (int p = 0; p < 4; ++p) acc2[p] = mfma16(a2h[p][c + 2], B2l[c], acc2[p]);
#pragma unroll
      for (int p = 0; p < 4; ++p) acc2[p] = mfma16(a2l[p][c + 2], B2h[c], acc2[p]);
    }

    float h2n[4];
#pragma unroll
    for (int r = 0; r < 4; ++r) {
      const float ig = sigm(acc2[0][r]), fg = sigm(acc2[1][r]);
      const float gg = tanh_f(acc2[2][r]), og = sigm(acc2[3][r]);
      c2[r] = fg * c2[r] + ig * gg;
      h2n[r] = og * tanh_f(c2[r]);
    }
    {  // pack h2 -> planes 2,3 of write-buffer
      const unsigned hA = cvt_pk(h2n[0], h2n[1]), hB = cvt_pk(h2n[2], h2n[3]);
      const float l0 = h2n[0] - __uint_as_float(hA << 16);
      const float l1 = h2n[1] - __uint_as_float(hA & 0xFFFF0000u);
      const float l2 = h2n[2] - __uint_as_float(hB << 16);
      const float l3 = h2n[3] - __uint_as_float(hB & 0xFFFF0000u);
      const unsigned lA = cvt_pk(l0, l1), lB = cvt_pk(l2, l3);
      const int hoff = s * 144 + 32 * w + 8 * g;
      *(uint2*)(smem + wb + 2 * 2304 + hoff) = make_uint2(hA, hB);
      *(uint2*)(smem + wb + 3 * 2304 + hoff) = make_uint2(lA, lB);
    }

    // ---- output partial: out[s] = sum_j Wlin[j] h2[j][s] + b ----
    float pw = wlinc[0] * h2n[0];
    pw = fmaf(wlinc[1], h2n[1], pw);
    pw = fmaf(wlinc[2], h2n[2], pw);
    pw = fmaf(wlinc[3], h2n[3], pw);
    pw += __shfl_xor(pw, 16, 64);
    pw += __shfl_xor(pw, 32, 64);
    if (g == 0) *(float*)(smem + OP + w * 64 + s * 4) = pw;
    __syncthreads();  // h2new + outp visible

    const float oo = *(const float*)(smem + OP + s * 4) +
                     *(const float*)(smem + OP + 64 + s * 4) +
                     *(const float*)(smem + OP + 128 + s * 4) +
                     *(const float*)(smem + OP + 192 + s * 4) + bl0;
    if (w == 0 && g == 0 && t >= 1) out[(size_t)(s0 + s) * 511 + t - 1] = oo;
  }
}

extern "C" void kernel_launch(void* const* d_in, const int* in_sizes, int n_in,
                              void* d_out, int out_size, void* d_ws, size_t ws_size,
                              hipStream_t stream) {
  const float* y    = (const float*)d_in[0];
  const float* Wih1 = (const float*)d_in[1];
  const float* Whh1 = (const float*)d_in[2];
  const float* bih1 = (const float*)d_in[3];
  const float* bhh1 = (const float*)d_in[4];
  const float* Wih2 = (const float*)d_in[5];
  const float* Whh2 = (const float*)d_in[6];
  const float* bih2 = (const float*)d_in[7];
  const float* bhh2 = (const float*)d_in[8];
  const float* Wlin = (const float*)d_in[9];
  const float* blin = (const float*)d_in[10];
  float* out = (float*)d_out;

  hipFuncSetAttribute((const void*)lstm2_mfma,
                      hipFuncAttributeMaxDynamicSharedMemorySize, LDS_BYTES);
  lstm2_mfma<<<dim3(128), dim3(256), LDS_BYTES, stream>>>(
      y, Wih1, Whh1, bih1, bhh1, Wih2, Whh2, bih2, bhh2, Wlin, blin, out);
}